// Round 9
// baseline (154.432 us; speedup 1.0000x reference)
//
#include <hip/hip_runtime.h>
#include <hip/hip_bf16.h>
#include <stdint.h>

typedef __bf16 bf16_t;
typedef bf16_t bf16x8 __attribute__((ext_vector_type(8)));
typedef float f32x4 __attribute__((ext_vector_type(4)));

#define BM 256
#define BN 256
#define BK 64

// ---------------------------------------------------------------------------
// async global->LDS 16B copy. LDS dest is wave-uniform base; HW adds lane*16.
// ---------------------------------------------------------------------------
__device__ __forceinline__ void gload_lds16(const void* g, void* l) {
  __builtin_amdgcn_global_load_lds(
      (const __attribute__((address_space(1))) uint32_t*)g,
      (__attribute__((address_space(3))) uint32_t*)l, 16, 0, 0);
}

// ---------------------------------------------------------------------------
// fused fp32->bf16 conversion: blocks [0,gx) convert x, [gx,..) convert
// weight (per-out-channel scale folded in). 8 elems/thread, grid-stride.
// ---------------------------------------------------------------------------
__global__ __launch_bounds__(256) void cvt_kernel(
    const float* __restrict__ x, bf16_t* __restrict__ xo, int n8x,
    const float* __restrict__ w, const float* __restrict__ scale,
    bf16_t* __restrict__ wo, int k8, int n8w, int gx) {
  if ((int)blockIdx.x < gx) {
    int stride = gx * blockDim.x;
    for (int i = blockIdx.x * blockDim.x + threadIdx.x; i < n8x; i += stride) {
      const f32x4* p = (const f32x4*)x + 2 * (size_t)i;
      f32x4 a = p[0], b = p[1];
      bf16x8 o;
#pragma unroll
      for (int r = 0; r < 4; ++r) { o[r] = (bf16_t)a[r]; o[r + 4] = (bf16_t)b[r]; }
      *((bf16x8*)xo + i) = o;
    }
  } else {
    int stride = (gridDim.x - gx) * blockDim.x;
    for (int i = (blockIdx.x - gx) * blockDim.x + threadIdx.x; i < n8w;
         i += stride) {
      int row = i / k8;
      float s = scale[row];
      const f32x4* p = (const f32x4*)w + 2 * (size_t)i;
      f32x4 a = p[0], b = p[1];
      bf16x8 o;
#pragma unroll
      for (int r = 0; r < 4; ++r) {
        o[r] = (bf16_t)(a[r] * s);
        o[r + 4] = (bf16_t)(b[r] * s);
      }
      *((bf16x8*)wo + i) = o;
    }
  }
}

// ---------------------------------------------------------------------------
// 256x256 bf16 GEMM, both K-major (B^T), 16x16x32 MFMA.
// r4 schedule (measured best: 136 us, MfmaUtil 45, 0 conflicts) with ONE
// change: the end-P2 barrier is deleted -> 3 barriers/K-tile.
//
// Barrier-necessity ledger (why end-P1/P3/P4 stay, end-P2 goes):
//  end-P1 KEEP: wave-B's P4(t-1) prefetch-reads of bb+0 / bb+32768 (A/B-K0(t))
//    drain only at wave-B's P1(t) lgkm(4). Wave-A's P3(t)/P4(t) stage-writes
//    to those regions must be ordered after -> end-P1 is the separator.
//  end-P2 DELETE: every stage after it vs read before it still has >=1
//    barrier after the reader's lgkm drain:
//      P3(t) stage bb+0      vs P4(t-1) reads: end-P1(t) [kept]
//      P4(t) stage bb+32768  vs P4(t-1) reads: end-P1(t), end-P3(t)
//      P2(t) stage nb+49152  vs P2(t-1) b1-reads (drain @P2(t-1) lgkm(8)):
//        end-P3(t-1), end-P4(t-1), end-P1(t)
//      P1(t) stage nb+16384  vs P3(t-1) aY-reads (drain @P4(t-1) lgkm(8)):
//        end-P4(t-1)
//    P3's reads (A-K1(t)) were staged P1(t-1), drained vmcnt(4)@P4(t-1) and
//    published by BAR@end-P4(t-1) -> no barrier needed between P2 and P3.
//  end-P3 KEEP: publishes vmcnt(6) drain of A/B-K0(t+1) for P4's reads.
//  end-P4 KEEP: publishes vmcnt(4) drain of A/B-K1(t+1) for P2(t+1)'s reads.
//
// lgkm FIFO (per-wave, barrier-independent): P1 issues 4 -> lgkm(4) drains
// P4(t-1)'s 8 (aX,b0 = P1 MFMA operands); P2 issues 8 -> lgkm(8) drains aY;
// P3 issues 4 -> lgkm(4) drains aX,b1; P4 issues 8 -> lgkm(8) drains aY.
//
// LDS swizzle: chunk-XOR s(row)=(row>>1)&3 at 16B granularity — measured
// 0 SQ_LDS_BANK_CONFLICT; staging pre-applies it on the global source.
// ---------------------------------------------------------------------------
__global__ __launch_bounds__(512, 2) void gemm256(
    const bf16_t* __restrict__ A, const bf16_t* __restrict__ B,
    const float* __restrict__ bias, float* __restrict__ C,
    int M, int N, int K) {
  __shared__ __attribute__((aligned(16))) char lds[131072];

  const int tid = threadIdx.x;
  const int lane = tid & 63;
  const int wave = tid >> 6;
  const int wm = wave >> 2;   // 0..1  (row half of tile)
  const int wn = wave & 3;    // 0..3  (col quarter of tile)

  // XCD-aware bijective swizzle
  int nwg = gridDim.x;
  int wg = blockIdx.x;
  if ((nwg & 7) == 0) { int cpx = nwg >> 3; wg = (wg & 7) * cpx + (wg >> 3); }
  const int ntn = N / BN;
  const int tm = wg / ntn;
  const int tn = wg % ntn;

  const size_t Kb = (size_t)K * 2;
  const char* gApan = (const char*)A + (size_t)tm * BM * Kb;
  const char* gBpan = (const char*)B + (size_t)tn * BN * Kb;

  // ---- per-lane read bases (row*64 + swizzled 16B chunk) ----
  const int xc = (((lane >> 4) ^ ((lane >> 1) & 3)) << 4);
  const int aBase = (wm * 128 + (lane & 15)) * 64 + xc;  // + ch*4096 + i*1024
  const int bBase = (wn * 64 + (lane & 15)) * 64 + xc;   // + j*1024

  // ---- staging offsets: wave w covers rows [(2w+s)*16, +16) of a unit ----
  size_t srcoff[2];
  int ldst[2];
#pragma unroll
  for (int s = 0; s < 2; ++s) {
    int r = (wave * 2 + s) * 16 + (lane >> 2);
    int c = (lane & 3) ^ ((lane >> 3) & 3);
    srcoff[s] = (size_t)r * Kb + (size_t)(c << 4);
    ldst[s] = (wave * 2 + s) * 1024;
  }

#define STAGE_U(dstbase, pan, kbyte)                                          \
  {                                                                           \
    gload_lds16((pan) + srcoff[0] + (size_t)(kbyte), lds + (dstbase) + ldst[0]); \
    gload_lds16((pan) + srcoff[1] + (size_t)(kbyte), lds + (dstbase) + ldst[1]); \
  }
#define RD_A(dst, base, ch)                                                   \
  _Pragma("unroll") for (int i_ = 0; i_ < 4; ++i_)                            \
      dst[i_] = *(const bf16x8*)((base) + aoff[ch][i_]);
#define RD_B(dst, base)                                                       \
  _Pragma("unroll") for (int j_ = 0; j_ < 4; ++j_)                            \
      dst[j_] = *(const bf16x8*)((base) + boff[j_]);
#define MFMA16(ab, bb_, accbase)                                              \
  __builtin_amdgcn_s_setprio(1);                                              \
  _Pragma("unroll") for (int i_ = 0; i_ < 4; ++i_)                            \
      _Pragma("unroll") for (int j_ = 0; j_ < 4; ++j_)                        \
          acc[(accbase) + i_][j_] = __builtin_amdgcn_mfma_f32_16x16x32_bf16(  \
              ab[i_], bb_[j_], acc[(accbase) + i_][j_], 0, 0, 0);             \
  __builtin_amdgcn_s_setprio(0);
#define WAIT_LGKM(n) asm volatile("s_waitcnt lgkmcnt(" #n ")" ::: "memory")
#define WAIT_VM(n)   asm volatile("s_waitcnt vmcnt(" #n ")" ::: "memory")
#define BAR()        __builtin_amdgcn_s_barrier()

  // per-lane ds_read offsets (as in r4)
  int aoff[2][4], boff[4];
#pragma unroll
  for (int ch = 0; ch < 2; ++ch)
#pragma unroll
    for (int i = 0; i < 4; ++i) aoff[ch][i] = aBase + ch * 4096 + i * 1024;
#pragma unroll
  for (int j = 0; j < 4; ++j) boff[j] = bBase + j * 1024;

  f32x4 acc[8][4];
#pragma unroll
  for (int a = 0; a < 8; ++a)
#pragma unroll
    for (int j = 0; j < 4; ++j) acc[a][j] = (f32x4)0.0f;

  const int NT = K / BK;

  // ---- prologue: tile0 (4 units) + tile1 K0 (2 units); 2 left in flight ----
  STAGE_U(0,             gApan, 0);
  STAGE_U(32768,         gBpan, 0);
  STAGE_U(16384,         gApan, 64);
  STAGE_U(49152,         gBpan, 64);
  if (NT > 1) {
    STAGE_U(65536,         gApan, 128);
    STAGE_U(65536 + 32768, gBpan, 128);
    WAIT_VM(4);
  } else {
    WAIT_VM(0);
  }
  BAR();

  bf16x8 aX[4], aY[4], b0[4], b1[4];
  RD_A(aX, lds + 0, 0);       // A(ch0,K0) tile0
  RD_B(b0, lds + 32768);      // B-K0 tile0

  for (int t = 0; t < NT; ++t) {
    const int bb = (t & 1) << 16;
    const int nb = bb ^ 65536;
    const size_t kb1 = (size_t)(t + 1) * 128;
    const size_t kb2 = (size_t)(t + 2) * 128;
    const bool st1 = (t + 1) < NT;
    const bool st2 = (t + 2) < NT;

    const char* lA0 = lds + bb;
    const char* lA1 = lds + bb + 16384;
    const char* lB1 = lds + bb + 49152;

    // ---- P1: MFMA(aX=A ch0 K0, b0) ; prefetch aY = A ch1 K0 ----
    RD_A(aY, lA0, 1);
    if (st1) STAGE_U(nb + 16384, gApan, kb1 + 64);   // A-K1(t+1)
    WAIT_LGKM(4);
    MFMA16(aX, b0, 0);
    BAR();   // KEEP: separates P4(t-1) prefetch-reads from P3/P4(t) stages

    // ---- P2: MFMA(aY, b0) ; prefetch aX = A ch0 K1, b1 = B-K1 ----
    RD_A(aX, lA1, 0);
    RD_B(b1, lB1);
    if (st1) STAGE_U(nb + 49152, gBpan, kb1 + 64);   // B-K1(t+1)
    WAIT_LGKM(8);
    MFMA16(aY, b0, 4);
    // (end-P2 barrier deleted — see ledger above)

    // ---- P3: MFMA(aX, b1) ; prefetch aY = A ch1 K1 ----
    RD_A(aY, lA1, 1);
    if (st2) STAGE_U(bb, gApan, kb2);                // A-K0(t+2)
    WAIT_LGKM(4);
    MFMA16(aX, b1, 0);
    WAIT_VM(6);   // drains A/B-K0(t+1): nb K0 regions readable next phase
    BAR();   // KEEP: publishes the vmcnt(6) drain

    // ---- P4: MFMA(aY, b1) ; prefetch next tile's aX, b0 ----
    if (st1) {
      RD_A(aX, lds + nb, 0);        // A(ch0,K0) of t+1
      RD_B(b0, lds + nb + 32768);   // B-K0 of t+1
    }
    if (st2) STAGE_U(bb + 32768, gBpan, kb2);        // B-K0(t+2)
    if (st1) { WAIT_LGKM(8); } else { WAIT_LGKM(0); }
    MFMA16(aY, b1, 4);
    WAIT_VM(4);   // drains A/B-K1(t+1): lA1/lB1 readable from P2(t+1)
    BAR();   // KEEP: publishes the vmcnt(4) drain
  }
#undef STAGE_U
#undef RD_A
#undef RD_B
#undef MFMA16
#undef WAIT_LGKM
#undef WAIT_VM
#undef BAR

  // ---- epilogue: bias + store. C/D: col=lane&15, row=(lane>>4)*4+r ----
  const int row0 = tm * BM + wm * 128;
  const int col0 = tn * BN + wn * 64;
#pragma unroll
  for (int j = 0; j < 4; ++j) {
    int c = col0 + j * 16 + (lane & 15);
    float bv = bias[c];
#pragma unroll
    for (int a = 0; a < 8; ++a) {
      int ch = a >> 2, i = a & 3;
      int rbase = row0 + ch * 64 + i * 16 + ((lane >> 4) << 2);
#pragma unroll
      for (int r = 0; r < 4; ++r)
        C[(size_t)(rbase + r) * N + c] = acc[a][j][r] + bv;
    }
  }
}

// ---------------------------------------------------------------------------
// fallback: naive fp32 (only if workspace/shape unsuitable — correctness net)
// ---------------------------------------------------------------------------
__global__ void fallback_gemm(const float* __restrict__ x,
                              const float* __restrict__ w,
                              const float* __restrict__ s,
                              const float* __restrict__ b,
                              float* __restrict__ out, int M, int N, int K) {
  int o = blockIdx.x * blockDim.x + threadIdx.x;
  if (o >= M * N) return;
  int m = o / N, n = o % N;
  const float* xr = x + (size_t)m * K;
  const float* wr = w + (size_t)n * K;
  float acc = 0.f;
  for (int k = 0; k < K; ++k) acc += xr[k] * wr[k];
  out[o] = acc * s[n] + b[n];
}

extern "C" void kernel_launch(void* const* d_in, const int* in_sizes, int n_in,
                              void* d_out, int out_size, void* d_ws,
                              size_t ws_size, hipStream_t stream) {
  const float* x = (const float*)d_in[0];
  const float* w = (const float*)d_in[1];
  const float* sc = (const float*)d_in[2];
  const float* bias = (const float*)d_in[3];
  float* out = (float*)d_out;

  const int N = in_sizes[2];        // out_features (weight_scale length)
  const int K = in_sizes[1] / N;    // in_features
  const int M = in_sizes[0] / K;    // tokens

  const size_t need = ((size_t)M * K + (size_t)N * K) * sizeof(bf16_t);
  const bool fast = (ws_size >= need) && (M % BM == 0) && (N % BN == 0) &&
                    (K % BK == 0) && (K / BK >= 1);

  if (fast) {
    bf16_t* xb = (bf16_t*)d_ws;
    bf16_t* wb = xb + (size_t)M * K;

    int n8x = (M * K) / 8;
    int n8w = (N * K) / 8;
    const int gx = 2048;
    cvt_kernel<<<gx + 2048, 256, 0, stream>>>(x, xb, n8x, w, sc, wb, K / 8,
                                              n8w, gx);

    dim3 grid((M / BM) * (N / BN));
    gemm256<<<grid, 512, 0, stream>>>(xb, wb, bias, out, M, N, K);
  } else {
    int total = M * N;
    fallback_gemm<<<(total + 255) / 256, 256, 0, stream>>>(x, w, sc, bias, out,
                                                           M, N, K);
  }
}

// Round 10
// 153.626 us; speedup vs baseline: 1.0052x; 1.0052x over previous
//
#include <hip/hip_runtime.h>
#include <hip/hip_bf16.h>
#include <stdint.h>

typedef __bf16 bf16_t;
typedef bf16_t bf16x8 __attribute__((ext_vector_type(8)));
typedef float f32x4 __attribute__((ext_vector_type(4)));

#define BM 256
#define BN 256
#define BK 64

// ---------------------------------------------------------------------------
// async global->LDS 16B copy. LDS dest is wave-uniform base; HW adds lane*16.
// ---------------------------------------------------------------------------
__device__ __forceinline__ void gload_lds16(const void* g, void* l) {
  __builtin_amdgcn_global_load_lds(
      (const __attribute__((address_space(1))) uint32_t*)g,
      (__attribute__((address_space(3))) uint32_t*)l, 16, 0, 0);
}

// ---------------------------------------------------------------------------
// fused fp32->bf16 conversion: blocks [0,gx) convert x, [gx,..) convert
// weight (per-out-channel scale folded in). 8 elems/thread, grid-stride.
// ---------------------------------------------------------------------------
__global__ __launch_bounds__(256) void cvt_kernel(
    const float* __restrict__ x, bf16_t* __restrict__ xo, int n8x,
    const float* __restrict__ w, const float* __restrict__ scale,
    bf16_t* __restrict__ wo, int k8, int n8w, int gx) {
  if ((int)blockIdx.x < gx) {
    int stride = gx * blockDim.x;
    for (int i = blockIdx.x * blockDim.x + threadIdx.x; i < n8x; i += stride) {
      const f32x4* p = (const f32x4*)x + 2 * (size_t)i;
      f32x4 a = p[0], b = p[1];
      bf16x8 o;
#pragma unroll
      for (int r = 0; r < 4; ++r) { o[r] = (bf16_t)a[r]; o[r + 4] = (bf16_t)b[r]; }
      *((bf16x8*)xo + i) = o;
    }
  } else {
    int stride = (gridDim.x - gx) * blockDim.x;
    for (int i = (blockIdx.x - gx) * blockDim.x + threadIdx.x; i < n8w;
         i += stride) {
      int row = i / k8;
      float s = scale[row];
      const f32x4* p = (const f32x4*)w + 2 * (size_t)i;
      f32x4 a = p[0], b = p[1];
      bf16x8 o;
#pragma unroll
      for (int r = 0; r < 4; ++r) {
        o[r] = (bf16_t)(a[r] * s);
        o[r + 4] = (bf16_t)(b[r] * s);
      }
      *((bf16x8*)wo + i) = o;
    }
  }
}

// ---------------------------------------------------------------------------
// 256x256 bf16 GEMM, both K-major (B^T), 16x16x32 MFMA.
// K-loop = r9 (measured best: 134.4 us, MfmaUtil 45.5, 0 conflicts):
// 4 phases/K-tile, 3 barriers/K-tile, cross-phase register prefetch,
// counted vmcnt(6)@P3 / vmcnt(4)@P4 (never 0 mid-loop). Full hazard ledger
// in r9's comment block (unchanged; K-loop byte-identical).
//
// r10 delta: EPILOGUE ONLY — per-wave LDS-transpose store.
//   Old: global_store_dword with 4-rows-x-64B partial-line pattern ->
//        ~19MB C RFO in FETCH + ~25% write amplification, serial tail burst.
//   New: after the final K-loop barrier each wave reuses its own 16KB LDS
//        slice (no cross-wave sharing -> no extra barrier): acc -> LDS
//        (bank-swizzle col ^= bits{2,4} of f2(row)=(row>>2)&3; write 2-way,
//        read-b128 2-way = free), then ds_read_b128 + global_store_dwordx4:
//        wave writes 4 rows x 256B contiguous = full cachelines.
//
// LDS swizzle (K-loop): chunk-XOR s(row)=(row>>1)&3 at 16B granularity —
// measured 0 SQ_LDS_BANK_CONFLICT; staging pre-applies it on the global src.
// ---------------------------------------------------------------------------
__global__ __launch_bounds__(512, 2) void gemm256(
    const bf16_t* __restrict__ A, const bf16_t* __restrict__ B,
    const float* __restrict__ bias, float* __restrict__ C,
    int M, int N, int K) {
  __shared__ __attribute__((aligned(16))) char lds[131072];

  const int tid = threadIdx.x;
  const int lane = tid & 63;
  const int wave = tid >> 6;
  const int wm = wave >> 2;   // 0..1  (row half of tile)
  const int wn = wave & 3;    // 0..3  (col quarter of tile)

  // XCD-aware bijective swizzle
  int nwg = gridDim.x;
  int wg = blockIdx.x;
  if ((nwg & 7) == 0) { int cpx = nwg >> 3; wg = (wg & 7) * cpx + (wg >> 3); }
  const int ntn = N / BN;
  const int tm = wg / ntn;
  const int tn = wg % ntn;

  const size_t Kb = (size_t)K * 2;
  const char* gApan = (const char*)A + (size_t)tm * BM * Kb;
  const char* gBpan = (const char*)B + (size_t)tn * BN * Kb;

  // ---- per-lane read bases (row*64 + swizzled 16B chunk) ----
  const int xc = (((lane >> 4) ^ ((lane >> 1) & 3)) << 4);
  const int aBase = (wm * 128 + (lane & 15)) * 64 + xc;  // + ch*4096 + i*1024
  const int bBase = (wn * 64 + (lane & 15)) * 64 + xc;   // + j*1024

  // ---- staging offsets: wave w covers rows [(2w+s)*16, +16) of a unit ----
  size_t srcoff[2];
  int ldst[2];
#pragma unroll
  for (int s = 0; s < 2; ++s) {
    int r = (wave * 2 + s) * 16 + (lane >> 2);
    int c = (lane & 3) ^ ((lane >> 3) & 3);
    srcoff[s] = (size_t)r * Kb + (size_t)(c << 4);
    ldst[s] = (wave * 2 + s) * 1024;
  }

#define STAGE_U(dstbase, pan, kbyte)                                          \
  {                                                                           \
    gload_lds16((pan) + srcoff[0] + (size_t)(kbyte), lds + (dstbase) + ldst[0]); \
    gload_lds16((pan) + srcoff[1] + (size_t)(kbyte), lds + (dstbase) + ldst[1]); \
  }
#define RD_A(dst, base, ch)                                                   \
  _Pragma("unroll") for (int i_ = 0; i_ < 4; ++i_)                            \
      dst[i_] = *(const bf16x8*)((base) + aoff[ch][i_]);
#define RD_B(dst, base)                                                       \
  _Pragma("unroll") for (int j_ = 0; j_ < 4; ++j_)                            \
      dst[j_] = *(const bf16x8*)((base) + boff[j_]);
#define MFMA16(ab, bb_, accbase)                                              \
  __builtin_amdgcn_s_setprio(1);                                              \
  _Pragma("unroll") for (int i_ = 0; i_ < 4; ++i_)                            \
      _Pragma("unroll") for (int j_ = 0; j_ < 4; ++j_)                        \
          acc[(accbase) + i_][j_] = __builtin_amdgcn_mfma_f32_16x16x32_bf16(  \
              ab[i_], bb_[j_], acc[(accbase) + i_][j_], 0, 0, 0);             \
  __builtin_amdgcn_s_setprio(0);
#define WAIT_LGKM(n) asm volatile("s_waitcnt lgkmcnt(" #n ")" ::: "memory")
#define WAIT_VM(n)   asm volatile("s_waitcnt vmcnt(" #n ")" ::: "memory")
#define BAR()        __builtin_amdgcn_s_barrier()

  // per-lane ds_read offsets
  int aoff[2][4], boff[4];
#pragma unroll
  for (int ch = 0; ch < 2; ++ch)
#pragma unroll
    for (int i = 0; i < 4; ++i) aoff[ch][i] = aBase + ch * 4096 + i * 1024;
#pragma unroll
  for (int j = 0; j < 4; ++j) boff[j] = bBase + j * 1024;

  f32x4 acc[8][4];
#pragma unroll
  for (int a = 0; a < 8; ++a)
#pragma unroll
    for (int j = 0; j < 4; ++j) acc[a][j] = (f32x4)0.0f;

  const int NT = K / BK;

  // ---- prologue: tile0 (4 units) + tile1 K0 (2 units); 2 left in flight ----
  STAGE_U(0,             gApan, 0);
  STAGE_U(32768,         gBpan, 0);
  STAGE_U(16384,         gApan, 64);
  STAGE_U(49152,         gBpan, 64);
  if (NT > 1) {
    STAGE_U(65536,         gApan, 128);
    STAGE_U(65536 + 32768, gBpan, 128);
    WAIT_VM(4);
  } else {
    WAIT_VM(0);
  }
  BAR();

  bf16x8 aX[4], aY[4], b0[4], b1[4];
  RD_A(aX, lds + 0, 0);       // A(ch0,K0) tile0
  RD_B(b0, lds + 32768);      // B-K0 tile0

  for (int t = 0; t < NT; ++t) {
    const int bb = (t & 1) << 16;
    const int nb = bb ^ 65536;
    const size_t kb1 = (size_t)(t + 1) * 128;
    const size_t kb2 = (size_t)(t + 2) * 128;
    const bool st1 = (t + 1) < NT;
    const bool st2 = (t + 2) < NT;

    const char* lA0 = lds + bb;
    const char* lA1 = lds + bb + 16384;
    const char* lB1 = lds + bb + 49152;

    // ---- P1: MFMA(aX=A ch0 K0, b0) ; prefetch aY = A ch1 K0 ----
    RD_A(aY, lA0, 1);
    if (st1) STAGE_U(nb + 16384, gApan, kb1 + 64);   // A-K1(t+1)
    WAIT_LGKM(4);
    MFMA16(aX, b0, 0);
    BAR();   // KEEP: separates P4(t-1) prefetch-reads from P3/P4(t) stages

    // ---- P2: MFMA(aY, b0) ; prefetch aX = A ch0 K1, b1 = B-K1 ----
    RD_A(aX, lA1, 0);
    RD_B(b1, lB1);
    if (st1) STAGE_U(nb + 49152, gBpan, kb1 + 64);   // B-K1(t+1)
    WAIT_LGKM(8);
    MFMA16(aY, b0, 4);
    // (end-P2 barrier deleted — r9 ledger)

    // ---- P3: MFMA(aX, b1) ; prefetch aY = A ch1 K1 ----
    RD_A(aY, lA1, 1);
    if (st2) STAGE_U(bb, gApan, kb2);                // A-K0(t+2)
    WAIT_LGKM(4);
    MFMA16(aX, b1, 0);
    WAIT_VM(6);   // drains A/B-K0(t+1)
    BAR();   // KEEP: publishes the vmcnt(6) drain

    // ---- P4: MFMA(aY, b1) ; prefetch next tile's aX, b0 ----
    if (st1) {
      RD_A(aX, lds + nb, 0);        // A(ch0,K0) of t+1
      RD_B(b0, lds + nb + 32768);   // B-K0 of t+1
    }
    if (st2) STAGE_U(bb + 32768, gBpan, kb2);        // B-K0(t+2)
    if (st1) { WAIT_LGKM(8); } else { WAIT_LGKM(0); }
    MFMA16(aY, b1, 4);
    WAIT_VM(4);   // drains A/B-K1(t+1)
    BAR();   // KEEP: publishes the vmcnt(4) drain
  }
#undef STAGE_U
#undef RD_A
#undef RD_B
#undef MFMA16
#undef BAR

  // ---- epilogue: per-wave LDS transpose -> coalesced dwordx4 stores ----
  // Final K-loop BAR guarantees every wave's LDS reads are drained; each
  // wave reuses only its own 16KB slice -> no further barriers needed.
  {
    float* wlds = (float*)(lds + wave * 16384);
    const int hi4 = lane >> 4;      // 0..3
    const int lo = lane & 15;
    const int row0 = tm * BM + wm * 128;
    const int col0 = tn * BN + wn * 64;
    float bv[4];
#pragma unroll
    for (int j = 0; j < 4; ++j) bv[j] = bias[col0 + j * 16 + lo];

#pragma unroll
    for (int ch = 0; ch < 2; ++ch) {
      // write 64x64 f32 (rows = ch-half of wave tile) into LDS, swizzled:
      // colx = col ^ ((f2&1)<<2) ^ ((f2&2)<<3), f2(row) = (row>>2)&3.
      // Here row = i*16 + hi4*4 + r -> f2 = hi4. Write conflicts: 2-way.
#pragma unroll
      for (int i = 0; i < 4; ++i) {
#pragma unroll
        for (int j = 0; j < 4; ++j) {
#pragma unroll
          for (int r = 0; r < 4; ++r) {
            int row = i * 16 + hi4 * 4 + r;
            int colx = (j * 16 + lo) ^ ((hi4 & 1) << 2) ^ ((hi4 & 2) << 3);
            wlds[row * 64 + colx] = acc[ch * 4 + i][j][r] + bv[j];
          }
        }
      }
      WAIT_LGKM(0);   // own-wave ds_write -> ds_read ordering
      // read back float4 (row rr = s*4+hi4 -> f2 = s&3) and store coalesced:
      // wave stores 4 rows x 256B contiguous per iteration (full lines).
#pragma unroll
      for (int s = 0; s < 16; ++s) {
        int rr = s * 4 + hi4;
        int c4 = lo ^ (s & 1) ^ (((s >> 1) & 1) << 2);
        f32x4 v = *(const f32x4*)(wlds + rr * 64 + c4 * 4);
        float* gp = &C[(size_t)(row0 + ch * 64 + rr) * N + col0 + lo * 4];
        *(f32x4*)gp = v;
      }
    }
  }
#undef WAIT_LGKM
#undef WAIT_VM
}

// ---------------------------------------------------------------------------
// fallback: naive fp32 (only if workspace/shape unsuitable — correctness net)
// ---------------------------------------------------------------------------
__global__ void fallback_gemm(const float* __restrict__ x,
                              const float* __restrict__ w,
                              const float* __restrict__ s,
                              const float* __restrict__ b,
                              float* __restrict__ out, int M, int N, int K) {
  int o = blockIdx.x * blockDim.x + threadIdx.x;
  if (o >= M * N) return;
  int m = o / N, n = o % N;
  const float* xr = x + (size_t)m * K;
  const float* wr = w + (size_t)n * K;
  float acc = 0.f;
  for (int k = 0; k < K; ++k) acc += xr[k] * wr[k];
  out[o] = acc * s[n] + b[n];
}

extern "C" void kernel_launch(void* const* d_in, const int* in_sizes, int n_in,
                              void* d_out, int out_size, void* d_ws,
                              size_t ws_size, hipStream_t stream) {
  const float* x = (const float*)d_in[0];
  const float* w = (const float*)d_in[1];
  const float* sc = (const float*)d_in[2];
  const float* bias = (const float*)d_in[3];
  float* out = (float*)d_out;

  const int N = in_sizes[2];        // out_features (weight_scale length)
  const int K = in_sizes[1] / N;    // in_features
  const int M = in_sizes[0] / K;    // tokens

  const size_t need = ((size_t)M * K + (size_t)N * K) * sizeof(bf16_t);
  const bool fast = (ws_size >= need) && (M % BM == 0) && (N % BN == 0) &&
                    (K % BK == 0) && (N % 4 == 0) && (K / BK >= 1);

  if (fast) {
    bf16_t* xb = (bf16_t*)d_ws;
    bf16_t* wb = xb + (size_t)M * K;

    int n8x = (M * K) / 8;
    int n8w = (N * K) / 8;
    const int gx = 2048;
    cvt_kernel<<<gx + 2048, 256, 0, stream>>>(x, xb, n8x, w, sc, wb, K / 8,
                                              n8w, gx);

    dim3 grid((M / BM) * (N / BN));
    gemm256<<<grid, 512, 0, stream>>>(xb, wb, bias, out, M, N, K);
  } else {
    int total = M * N;
    fallback_gemm<<<(total + 255) / 256, 256, 0, stream>>>(x, w, sc, bias, out,
                                                           M, N, K);
  }
}